// Round 4
// baseline (460.916 us; speedup 1.0000x reference)
//
#include <hip/hip_runtime.h>
#include <stdint.h>

typedef unsigned int u32;
typedef unsigned short u16;
typedef unsigned char u8;
typedef unsigned long long u64;

#define DEV __device__ __forceinline__

constexpr int HWp = 9216;   // 96*96
constexpr int NB = 2;

// ---------- workspace layout (bytes) ----------
constexpr size_t O_IMG = 0;                          // f32 [b][48][9216]: th 0-15, ph 16-31, g 32-47
constexpr size_t N_IMG = (size_t)NB * 48 * HWp;      // 884736 floats
constexpr size_t O_ZI  = O_IMG + N_IMG * 4;          // f32 [b][16][9216] overlap-add accum
constexpr size_t N_ZI  = (size_t)NB * 16 * HWp;      // 294912 floats
constexpr size_t O_CT  = O_ZI + N_ZI * 4;            // f32 [b][9216] counts
constexpr size_t N_CT  = (size_t)NB * HWp;           // 18432 floats
constexpr size_t O_FLG = O_CT + N_CT * 4;            // 2 u32: vflag, wflag
constexpr size_t O_WT  = O_FLG + 16;                 // converted f32 weights
// WT offsets (in floats)
constexpr int W_TH = 0, B_TH = 1024, W_PH = 1040, B_PH = 2064, W_G = 2080, B_G = 3104,
              W_W = 3120, B_W = 4144, W_C = 4208, B_C = 12400, N_WT = 12464;
constexpr size_t WS_NEED = O_WT + (size_t)N_WT * 4;  // ~4.84 MB

DEV float bf2f(u16 x) { return __uint_as_float(((u32)x) << 16); }
DEV int clampi(int v, int lo, int hi) { return v < lo ? lo : (v > hi ? hi : v); }

// ---------- KZ: zero accumulators; detect dtypes; convert all weights to f32 stash ----------
__global__ __launch_bounds__(256) void kz_prep(
    const void* vid,
    const void* wth, const void* bth, const void* wph, const void* bph,
    const void* wg, const void* bg, const void* ww, const void* bw,
    const void* wc33, const void* bc33, u8* ws)
{
  int tid = threadIdx.x, blk = blockIdx.x;
  if (blk < 1224) {  // zero ZI + CT (contiguous 313344 floats)
    ((float*)(ws + O_ZI))[blk * 256 + tid] = 0.f;
    return;
  }
  // block 1224: dtype flags + weight conversion
  __shared__ int red[256];
  // vid dtype: f32 data read as u16 -> low halves uniform random -> "exponent byte" >= 0xC8
  // occurs ~11% of u16s; bf16 N(0,1) data: never.
  {
    const u16* p = (const u16*)vid;
    int h = 0;
    for (int i = tid; i < 8192; i += 256) h += ((((u32)p[i] >> 7) & 0xFFu) >= 0xC8u) ? 1 : 0;
    red[tid] = h;
  }
  __syncthreads();
  if (tid == 0) { int t = 0; for (int i = 0; i < 256; ++i) t += red[i]; red[0] = t; }
  __syncthreads();
  const bool vf = red[0] >= 32;
  __syncthreads();
  {
    const u16* p = (const u16*)wc33;  // 8192 elements -> safe to scan 8192 u16 either way
    int h = 0;
    for (int i = tid; i < 8192; i += 256) h += ((((u32)p[i] >> 7) & 0xFFu) >= 0xC8u) ? 1 : 0;
    red[tid] = h;
  }
  __syncthreads();
  if (tid == 0) { int t = 0; for (int i = 0; i < 256; ++i) t += red[i]; red[0] = t; }
  __syncthreads();
  const bool wf = red[0] >= 32;
  if (tid == 0) { ((u32*)(ws + O_FLG))[0] = vf ? 1u : 0u; ((u32*)(ws + O_FLG))[1] = wf ? 1u : 0u; }

  float* WT = (float*)(ws + O_WT);
  const void* srcs[10] = { wth, bth, wph, bph, wg, bg, ww, bw, wc33, bc33 };
  const int offs[10]   = { W_TH, B_TH, W_PH, B_PH, W_G, B_G, W_W, B_W, W_C, B_C };
  const int lens[10]   = { 1024, 16, 1024, 16, 1024, 16, 1024, 64, 8192, 64 };
  for (int a = 0; a < 10; ++a) {
    const void* s = srcs[a];
    for (int i = tid; i < lens[a]; i += 256)
      WT[offs[a] + i] = wf ? ((const float*)s)[i] : bf2f(((const u16*)s)[i]);
  }
}

// ---------- K1: conv1x1 -> theta/phi/g f32 planar images ----------
__global__ __launch_bounds__(256) void k1_conv(const void* vid, u8* ws)
{
  int gid = blockIdx.x * 256 + threadIdx.x;   // exact: 3456*256 = 2*48*9216
  int px = gid % HWp, t = gid / HWp, b = t / 48, o = t % 48;
  const float* WT = (const float*)(ws + O_WT);
  int wo, bo;
  if (o < 16)      { wo = W_TH + o * 64;        bo = B_TH + o; }
  else if (o < 32) { wo = W_PH + (o - 16) * 64; bo = B_PH + o - 16; }
  else             { wo = W_G  + (o - 32) * 64; bo = B_G  + o - 32; }
  float acc = WT[bo];
  const bool vf = ((const u32*)(ws + O_FLG))[0] != 0;
  if (vf) {
    const float* v = (const float*)vid;
    for (int c = 0; c < 64; ++c) acc += WT[wo + c] * v[(size_t)(b * 64 + c) * HWp + px];
  } else {
    const u16* v = (const u16*)vid;
    for (int c = 0; c < 64; ++c) acc += WT[wo + c] * bf2f(v[(size_t)(b * 64 + c) * HWp + px]);
  }
  ((float*)(ws + O_IMG))[(size_t)t * HWp + px] = acc;
}

// ---------- K2: per-query scores (direct double-clip), exact stable top-100, softmax, z + atomic scatter ----------
__global__ __launch_bounds__(256) void k2_attn(u8* ws)
{
  __shared__ float thL[784];     // [c*49 + di*7 + dj]
  __shared__ float scL[441];
  __shared__ float wgtL[100];    // UNnormalized softmax weights
  __shared__ u16 selL[100];
  __shared__ u8 crL[441], ccL[441];
  __shared__ float invL;

  const int tid = threadIdx.x, blk = blockIdx.x;
  const int b = blk / 576, q = blk % 576;
  const int qi = (q / 24) * 4, qj = (q % 24) * 4;
  const float* IMG = (const float*)(ws + O_IMG) + (size_t)b * 48 * HWp;

  for (int e = tid; e < 441; e += 256) {   // FIX: cover all 441 (was if(tid<441) with 256 threads)
    int d1 = e / 21, d2 = e % 21;
    crL[e] = (u8)clampi(qi + d1 - 10, 0, 95);
    ccL[e] = (u8)clampi(qj + d2 - 10, 0, 95);
  }
  for (int e = tid; e < 784; e += 256) {  // theta patch, f32
    int c = e / 49, p = e % 49, di = p / 7, dj = p % 7;
    thL[e] = IMG[(size_t)c * HWp + clampi(qi + di - 3, 0, 95) * 96 + clampi(qj + dj - 3, 0, 95)];
  }
  __syncthreads();

  for (int cc2 = 0; cc2 < 2; ++cc2) {  // scores: direct formula, f32
    int cand = tid + cc2 * 256;
    if (cand < 441) {
      int cr = crL[cand], cc = ccL[cand];
      int pyv[7], pxv[7];
#pragma unroll
      for (int i = 0; i < 7; ++i) { pyv[i] = clampi(cr + i - 3, 0, 95) * 96; pxv[i] = clampi(cc + i - 3, 0, 95); }
      float acc = 0.f;
      for (int c = 0; c < 16; ++c) {
        const float* ph = IMG + (size_t)(16 + c) * HWp;
        const float* tt = &thL[c * 49];
#pragma unroll
        for (int di = 0; di < 7; ++di) {
          const float* row = ph + pyv[di];
#pragma unroll
          for (int dj = 0; dj < 7; ++dj) acc += tt[di * 7 + dj] * row[pxv[dj]];
        }
      }
      scL[cand] = acc;
    }
  }
  __syncthreads();

  if (tid < 64) {  // wave 0: exact top-100, stable ties (lowest index first, as jax.lax.top_k)
    const int lane = tid;
    u64 kv[7];
#pragma unroll
    for (int s = 0; s < 7; ++s) {
      int idx = s * 64 + lane;
      if (idx < 441) {
        u32 bb = __float_as_uint(scL[idx]);
        u32 ob = (bb & 0x80000000u) ? ~bb : (bb | 0x80000000u);
        kv[s] = ((u64)ob << 32) | (u64)(511 - idx);   // ties: larger low bits = smaller idx wins
      } else kv[s] = 0ull;
    }
    float vmax = 0.f, denom = 0.f;
    for (int k = 0; k < 100; ++k) {
      u64 m = kv[0];
#pragma unroll
      for (int s = 1; s < 7; ++s) m = (kv[s] > m) ? kv[s] : m;
      for (int off = 1; off < 64; off <<= 1) { u64 o = __shfl_xor(m, off, 64); m = (o > m) ? o : m; }
      int idx = 511 - (int)(m & 0xFFFFFFFFull);
      u32 ob = (u32)(m >> 32);
      u32 bb = (ob & 0x80000000u) ? (ob & 0x7FFFFFFFu) : ~ob;
      float sc = __uint_as_float(bb);          // exact decode of the selected score
      if (k == 0) vmax = sc;
      float w = __expf(10.f * (sc - vmax));    // every lane computes the same value
      denom += w;
      if (lane == 0) selL[k] = (u16)idx;
      if (lane == (k & 63)) wgtL[k] = w;       // one writer per entry; read after barrier
      if (lane == (idx & 63)) kv[idx >> 6] = 0ull;   // remove selected from its owner lane
    }
    if (lane == 0) invL = 1.f / denom;
  }
  __syncthreads();

  // z = invD * sum_k w_k * g-patch_k, then literal scatter-add (mirrors reference .at[].add)
  float* ZI = (float*)(ws + O_ZI) + (size_t)b * 16 * HWp;
  float* CT = (float*)(ws + O_CT) + (size_t)b * HWp;
  const float* G = IMG + (size_t)32 * HWp;
  const float inv = invL;
  for (int e = tid; e < 784; e += 256) {
    int c = e / 49, p = e % 49, di = p / 7, dj = p % 7;
    float acc = 0.f;
    for (int k = 0; k < 100; ++k) {
      int si = selL[k];
      int py = clampi((int)crL[si] + di - 3, 0, 95);
      int px = clampi((int)ccL[si] + dj - 3, 0, 95);
      acc += wgtL[k] * G[(size_t)c * HWp + py * 96 + px];
    }
    acc *= inv;
    int oy = clampi(qi + di - 3, 0, 95), ox = clampi(qj + dj - 3, 0, 95);
    atomicAdd(&ZI[(size_t)c * HWp + oy * 96 + ox], acc);
    if (c == 0) atomicAdd(&CT[oy * 96 + ox], 1.0f);
  }
}

// ---------- K3: normalize, y = ww·zn + bw, out = wc33·[y ; vid] + bc33 -> f32 out ----------
__global__ __launch_bounds__(256) void k3_out(const void* vid, float* out, const u8* ws)
{
  __shared__ float zn[16 * 96];
  __shared__ float cat[128 * 96];   // rows 0..63 = y, 64..127 = vid
  const int tid = threadIdx.x, blk = blockIdx.x;
  const int b = blk / 96, y = blk % 96;
  const float* WT = (const float*)(ws + O_WT);
  const float* ZI = (const float*)(ws + O_ZI) + (size_t)b * 16 * HWp;
  const float* CT = (const float*)(ws + O_CT) + (size_t)b * HWp;
  const bool vf = ((const u32*)(ws + O_FLG))[0] != 0;

  for (int e = tid; e < 1536; e += 256) {
    int c = e / 96, x = e % 96;
    zn[c * 96 + x] = ZI[(size_t)c * HWp + y * 96 + x] / fmaxf(CT[y * 96 + x], 1.f);
  }
  if (vf) {
    const float* v = (const float*)vid;
    for (int e = tid; e < 6144; e += 256) {
      int c = e / 96, x = e % 96;
      cat[(64 + c) * 96 + x] = v[(size_t)(b * 64 + c) * HWp + y * 96 + x];
    }
  } else {
    const u16* v = (const u16*)vid;
    for (int e = tid; e < 6144; e += 256) {
      int c = e / 96, x = e % 96;
      cat[(64 + c) * 96 + x] = bf2f(v[(size_t)(b * 64 + c) * HWp + y * 96 + x]);
    }
  }
  __syncthreads();
  for (int e = tid; e < 6144; e += 256) {  // y-row
    int m = e / 96, x = e % 96;
    float a = WT[B_W + m];
#pragma unroll
    for (int ci = 0; ci < 16; ++ci) a += WT[W_W + m * 16 + ci] * zn[ci * 96 + x];
    cat[m * 96 + x] = a;
  }
  __syncthreads();
  const int o = tid >> 2, xq = tid & 3;
  for (int j = 0; j < 24; ++j) {
    int x = xq * 24 + j;
    float a = WT[B_C + o];
    for (int jj = 0; jj < 128; ++jj) a += WT[W_C + o * 128 + jj] * cat[jj * 96 + x];
    out[(size_t)(b * 64 + o) * HWp + y * 96 + x] = a;   // FLOAT32 output (reference dtype)
  }
}

extern "C" void kernel_launch(void* const* d_in, const int* in_sizes, int n_in,
                              void* d_out, int out_size, void* d_ws, size_t ws_size,
                              hipStream_t stream)
{
  (void)in_sizes; (void)n_in; (void)out_size;
  const void* vid  = d_in[0];
  const void* wth  = d_in[1];
  const void* bth  = d_in[2];
  const void* wph  = d_in[3];
  const void* bph  = d_in[4];
  const void* wg   = d_in[5];
  const void* bg   = d_in[6];
  const void* ww   = d_in[7];
  const void* bw   = d_in[8];
  const void* wc33 = d_in[9];
  const void* bc33 = d_in[10];
  u8* ws = (u8*)d_ws;
  if (ws_size < WS_NEED) return;

  hipLaunchKernelGGL(kz_prep, dim3(1225), dim3(256), 0, stream,
                     vid, wth, bth, wph, bph, wg, bg, ww, bw, wc33, bc33, ws);
  hipLaunchKernelGGL(k1_conv, dim3(3456), dim3(256), 0, stream, vid, ws);
  hipLaunchKernelGGL(k2_attn, dim3(1152), dim3(256), 0, stream, ws);
  hipLaunchKernelGGL(k3_out, dim3(192), dim3(256), 0, stream, vid, (float*)d_out, ws);
}

// Round 5
// 404.196 us; speedup vs baseline: 1.1403x; 1.1403x over previous
//
#include <hip/hip_runtime.h>
#include <stdint.h>

typedef unsigned int u32;
typedef unsigned short u16;
typedef unsigned char u8;
typedef unsigned long long u64;
typedef _Float16 h2 __attribute__((ext_vector_type(2)));
typedef _Float16 h4 __attribute__((ext_vector_type(4)));
typedef _Float16 h8 __attribute__((ext_vector_type(8)));
typedef float f4 __attribute__((ext_vector_type(4)));

#define DEV __device__ __forceinline__

constexpr int HWp = 9216;   // 96*96

// ---------- workspace layout (bytes) ----------
constexpr size_t O_I16 = 0;                          // f16 [b][9216][48]: th 0-15, ph 16-31, g 32-47
constexpr size_t N_I16 = 2ull * 9216 * 48;           // halves
constexpr size_t O_ZI  = O_I16 + N_I16 * 2;          // f32 [2][16][9216] overlap-add accum
constexpr size_t N_ZI  = 2ull * 16 * 9216;
constexpr size_t O_CT  = O_ZI + N_ZI * 4;            // f32 [2][9216] counts (contiguous after ZI)
constexpr size_t N_CT  = 2ull * 9216;
constexpr size_t O_FLG = O_CT + N_CT * 4;            // 2 u32: vflag, wflag
constexpr size_t O_WT  = O_FLG + 16;                 // f32 weight stash
constexpr int W_TH = 0, B_TH = 1024, W_PH = 1040, B_PH = 2064, W_G = 2080, B_G = 3104,
              W_W = 3120, B_W = 4144, W_C = 4208, B_C = 12400, N_WT = 12464;
constexpr size_t O_W1  = O_WT + (size_t)N_WT * 4;    // f32 [64][16] = wc33[:, :64] @ ww
constexpr size_t O_B0  = O_W1 + 1024 * 4;            // f32 [64] folded bias
constexpr size_t WS_NEED = O_B0 + 256;               // ~3.08 MB

DEV float bf2f(u16 x) { return __uint_as_float(((u32)x) << 16); }
DEV int clampi(int v, int lo, int hi) { return v < lo ? lo : (v > hi ? hi : v); }
DEV float loadIn(const void* base, size_t idx, bool isF32) {
  return isF32 ? ((const float*)base)[idx] : bf2f(((const u16*)base)[idx]);
}
DEV float dot2(h2 a, h2 b, float c) {
#if __has_builtin(__builtin_amdgcn_fdot2)
  return __builtin_amdgcn_fdot2(a, b, c, false);
#else
  return c + (float)a[0]*(float)b[0] + (float)a[1]*(float)b[1];
#endif
}
DEV float dot8(h8 a, h8 b, float c) {
  c = dot2(__builtin_shufflevector(a,a,0,1), __builtin_shufflevector(b,b,0,1), c);
  c = dot2(__builtin_shufflevector(a,a,2,3), __builtin_shufflevector(b,b,2,3), c);
  c = dot2(__builtin_shufflevector(a,a,4,5), __builtin_shufflevector(b,b,4,5), c);
  c = dot2(__builtin_shufflevector(a,a,6,7), __builtin_shufflevector(b,b,6,7), c);
  return c;
}

// ---------- KZ: zero accumulators; dtype flags; f32 weight stash; folded W1/B0 ----------
__global__ __launch_bounds__(256) void kz_prep(
    const void* vid,
    const void* wth, const void* bth, const void* wph, const void* bph,
    const void* wg, const void* bg, const void* ww, const void* bw,
    const void* wc33, const void* bc33, u8* ws)
{
  int tid = threadIdx.x, blk = blockIdx.x;
  if (blk < 1224) {  // zero ZI + CT (contiguous 313344 floats = 1224*256)
    ((float*)(ws + O_ZI))[blk * 256 + tid] = 0.f;
    return;
  }
  __shared__ int red[256];
  {
    const u16* p = (const u16*)vid;
    int h = 0;
    for (int i = tid; i < 8192; i += 256) h += ((((u32)p[i] >> 7) & 0xFFu) >= 0xC8u) ? 1 : 0;
    red[tid] = h;
  }
  __syncthreads();
  if (tid == 0) { int t = 0; for (int i = 0; i < 256; ++i) t += red[i]; red[0] = t; }
  __syncthreads();
  const bool vf = red[0] >= 32;
  __syncthreads();
  {
    const u16* p = (const u16*)wc33;
    int h = 0;
    for (int i = tid; i < 8192; i += 256) h += ((((u32)p[i] >> 7) & 0xFFu) >= 0xC8u) ? 1 : 0;
    red[tid] = h;
  }
  __syncthreads();
  if (tid == 0) { int t = 0; for (int i = 0; i < 256; ++i) t += red[i]; red[0] = t; }
  __syncthreads();
  const bool wf = red[0] >= 32;
  if (tid == 0) { ((u32*)(ws + O_FLG))[0] = vf ? 1u : 0u; ((u32*)(ws + O_FLG))[1] = wf ? 1u : 0u; }

  float* WT = (float*)(ws + O_WT);
  const void* srcs[10] = { wth, bth, wph, bph, wg, bg, ww, bw, wc33, bc33 };
  const int offs[10]   = { W_TH, B_TH, W_PH, B_PH, W_G, B_G, W_W, B_W, W_C, B_C };
  const int lens[10]   = { 1024, 16, 1024, 16, 1024, 16, 1024, 64, 8192, 64 };
  for (int a = 0; a < 10; ++a) {
    const void* s = srcs[a];
    for (int i = tid; i < lens[a]; i += 256)
      WT[offs[a] + i] = wf ? ((const float*)s)[i] : bf2f(((const u16*)s)[i]);
  }
  // folded W1[o][ci] = sum_j wc33[o][j]*ww[j][ci]; B0[o] = bc33[o] + sum_j wc33[o][j]*bw[j]
  float* W1 = (float*)(ws + O_W1);
  float* B0 = (float*)(ws + O_B0);
  for (int e = tid; e < 1024; e += 256) {
    int o = e >> 4, ci = e & 15;
    float s = 0.f;
    for (int c = 0; c < 64; ++c) s += loadIn(wc33, o*128 + c, wf) * loadIn(ww, c*16 + ci, wf);
    W1[e] = s;
  }
  if (tid < 64) {
    float s = loadIn(bc33, tid, wf);
    for (int c = 0; c < 64; ++c) s += loadIn(wc33, tid*128 + c, wf) * loadIn(bw, c, wf);
    B0[tid] = s;
  }
}

// ---------- K1: conv1x1 -> channel-last f16 image [b][px][48] ----------
__global__ __launch_bounds__(256, 2) void k1_conv(const void* vid, u8* ws)
{
  __shared__ float vidL[64 * 65];        // [px][c] pad 65
  __shared__ float wL[48 * 65];          // [o][c] pad 65
  __shared__ float bL[48];
  __shared__ __align__(16) _Float16 outL[64 * 48];
  int tid = threadIdx.x;
  int g0 = blockIdx.x * 64;
  int b = g0 / HWp, px0 = g0 % HWp;
  const float* WT = (const float*)(ws + O_WT);

  for (int e = tid; e < 3072; e += 256) {
    int o = e >> 6, c = e & 63;
    float w = (o < 16) ? WT[W_TH + o*64 + c] : (o < 32) ? WT[W_PH + (o-16)*64 + c] : WT[W_G + (o-32)*64 + c];
    wL[o*65 + c] = w;
  }
  if (tid < 48) bL[tid] = (tid < 16) ? WT[B_TH + tid] : (tid < 32) ? WT[B_PH + tid - 16] : WT[B_G + tid - 32];
  const bool vf = ((const u32*)(ws + O_FLG))[0] != 0;
  if (vf) {
    const float* v = (const float*)vid;
    for (int e = tid; e < 4096; e += 256) { int c = e >> 6, p = e & 63; vidL[p*65 + c] = v[(size_t)(b*64 + c)*HWp + px0 + p]; }
  } else {
    const u16* v = (const u16*)vid;
    for (int e = tid; e < 4096; e += 256) { int c = e >> 6, p = e & 63; vidL[p*65 + c] = bf2f(v[(size_t)(b*64 + c)*HWp + px0 + p]); }
  }
  __syncthreads();

  int px = tid >> 2, h = tid & 3;
  float acc[12];
#pragma unroll
  for (int j = 0; j < 12; ++j) acc[j] = bL[h*12 + j];
  for (int c = 0; c < 64; ++c) {
    float v = vidL[px*65 + c];
#pragma unroll
    for (int j = 0; j < 12; ++j) acc[j] += wL[(h*12 + j)*65 + c] * v;
  }
#pragma unroll
  for (int j = 0; j < 12; ++j) outL[px*48 + h*12 + j] = (_Float16)acc[j];
  __syncthreads();

  _Float16* img = (_Float16*)(ws + O_I16);
  for (int e = tid; e < 384; e += 256) {   // coalesced h8 stores: 64 px * 96 B contiguous
    int p = e / 6, seg = e % 6;
    *(h8*)(img + (size_t)(b*HWp + px0 + p)*48 + seg*8) = *(const h8*)&outL[p*48 + seg*8];
  }
}

// ---------- K2: LDS-tiled attention: f16 scores, exact top-100, softmax, pk_fma z, atomic scatter ----------
__global__ __launch_bounds__(256, 4) void k2_attn(u8* ws)
{
  __shared__ __align__(16) _Float16 tA[729*8], tB[729*8];  // phi(then g) ch0-7 / ch8-15 planes
  __shared__ __align__(16) _Float16 thA[49*8], thB[49*8];  // theta planes
  __shared__ float scL[441];
  __shared__ u8 crL[441], ccL[441];
  __shared__ u16 selL[100];
  __shared__ u32 wgtH[100];   // normalized weight as packed h2

  const int tid = threadIdx.x, blk = blockIdx.x;
  const int b = blk / 576, q = blk % 576;
  const int qi = (q / 24) * 4, qj = (q % 24) * 4;
  const _Float16* I = (const _Float16*)(ws + O_I16) + (size_t)b * HWp * 48;

  for (int e = tid; e < 441; e += 256) {
    int d1 = e / 21, d2 = e % 21;
    crL[e] = (u8)clampi(qi + d1 - 10, 0, 95);
    ccL[e] = (u8)clampi(qj + d2 - 10, 0, 95);
  }
  for (int e = tid; e < 98; e += 256) {   // theta patch
    int p = e >> 1, hf = e & 1, di = p / 7, dj = p % 7;
    int ty = clampi(qi + di - 3, 0, 95), tx = clampi(qj + dj - 3, 0, 95);
    *(h8*)&(hf ? thB : thA)[p*8] = *(const h8*)(I + (size_t)(ty*96 + tx)*48 + hf*8);
  }
  for (int e = tid; e < 1458; e += 256) { // phi tile: row t holds image row clip(qi-13+t)
    int p = e >> 1, hf = e & 1, row = p / 27, col = p % 27;
    int gy = clampi(qi - 13 + row, 0, 95), gx = clampi(qj - 13 + col, 0, 95);
    *(h8*)&(hf ? tB : tA)[p*8] = *(const h8*)(I + (size_t)(gy*96 + gx)*48 + 16 + hf*8);
  }
  __syncthreads();

  { // scores: direct double-clip rebased into tile; t = clip(py)-(qi-13) is exact
    int c0 = tid;
    int c1 = (tid < 185) ? tid + 256 : tid;
    int cr0 = crL[c0], cc0 = ccL[c0], cr1 = crL[c1], cc1 = ccL[c1];
    int ro0[7], co0[7], ro1[7], co1[7];
#pragma unroll
    for (int i = 0; i < 7; ++i) {
      ro0[i] = (clampi(cr0 + i - 3, 0, 95) - qi + 13) * 216;  // *27*8
      co0[i] = (clampi(cc0 + i - 3, 0, 95) - qj + 13) * 8;
      ro1[i] = (clampi(cr1 + i - 3, 0, 95) - qi + 13) * 216;
      co1[i] = (clampi(cc1 + i - 3, 0, 95) - qj + 13) * 8;
    }
    float a0 = 0.f, a1 = 0.f;
    for (int di = 0; di < 7; ++di) {
#pragma unroll
      for (int dj = 0; dj < 7; ++dj) {
        int pp = di*7 + dj;
        h8 ta = *(const h8*)&thA[pp*8];
        h8 tb = *(const h8*)&thB[pp*8];
        int o0 = ro0[di] + co0[dj], o1 = ro1[di] + co1[dj];
        a0 = dot8(ta, *(const h8*)&tA[o0], a0);
        a0 = dot8(tb, *(const h8*)&tB[o0], a0);
        a1 = dot8(ta, *(const h8*)&tA[o1], a1);
        a1 = dot8(tb, *(const h8*)&tB[o1], a1);
      }
    }
    scL[c0] = a0;
    if (tid < 185) scL[tid + 256] = a1;
  }
  __syncthreads();

  if (tid >= 64) {  // waves 1-3: restage tiles with g while wave 0 selects
    for (int e = tid - 64; e < 1458; e += 192) {
      int p = e >> 1, hf = e & 1, row = p / 27, col = p % 27;
      int gy = clampi(qi - 13 + row, 0, 95), gx = clampi(qj - 13 + col, 0, 95);
      *(h8*)&(hf ? tB : tA)[p*8] = *(const h8*)(I + (size_t)(gy*96 + gx)*48 + 32 + hf*8);
    }
  } else {  // wave 0: exact top-100 (R4-green), stable ties; pack normalized f16 weights
    const int lane = tid;
    u64 kv[7];
#pragma unroll
    for (int s = 0; s < 7; ++s) {
      int idx = s * 64 + lane;
      if (idx < 441) {
        u32 bb = __float_as_uint(scL[idx]);
        u32 ob = (bb & 0x80000000u) ? ~bb : (bb | 0x80000000u);
        kv[s] = ((u64)ob << 32) | (u64)(511 - idx);
      } else kv[s] = 0ull;
    }
    float vmax = 0.f, denom = 0.f, wA = 0.f, wB = 0.f;
    for (int k = 0; k < 100; ++k) {
      u64 m = kv[0];
#pragma unroll
      for (int s = 1; s < 7; ++s) m = (kv[s] > m) ? kv[s] : m;
      for (int off = 1; off < 64; off <<= 1) { u64 o = __shfl_xor(m, off, 64); m = (o > m) ? o : m; }
      int idx = 511 - (int)(m & 0xFFFFFFFFull);
      u32 ob = (u32)(m >> 32);
      u32 bb = (ob & 0x80000000u) ? (ob & 0x7FFFFFFFu) : ~ob;
      float sc = __uint_as_float(bb);
      if (k == 0) vmax = sc;
      float w = __expf(10.f * (sc - vmax));   // identical on all lanes
      denom += w;
      if (lane == 0) selL[k] = (u16)idx;
      if (lane == (k & 63)) { if (k < 64) wA = w; else wB = w; }
      if (lane == (idx & 63)) kv[idx >> 6] = 0ull;
    }
    float inv = 1.f / denom;
    { _Float16 wh = (_Float16)(wA * inv); h2 p2; p2[0] = wh; p2[1] = wh; wgtH[lane] = __builtin_bit_cast(u32, p2); }
    if (lane < 36) { _Float16 wh = (_Float16)(wB * inv); h2 p2; p2[0] = wh; p2[1] = wh; wgtH[lane + 64] = __builtin_bit_cast(u32, p2); }
  }
  __syncthreads();

  // z: thread = (pixel p, channel-quad cq); packed f16 accumulation; scatter-add
  if (tid < 196) {
    int p = tid >> 2, cq = tid & 3;
    int di = p / 7, dj = p % 7;
    const _Float16* base = (cq < 2 ? tA : tB) + (cq & 1) * 4;
    h2 accA; accA[0] = (_Float16)0.f; accA[1] = (_Float16)0.f;
    h2 accB = accA;
    for (int k = 0; k < 100; ++k) {
      int si = selL[k];
      int ty = clampi((int)crL[si] + di - 3, 0, 95) - qi + 13;
      int tx = clampi((int)ccL[si] + dj - 3, 0, 95) - qj + 13;
      h4 g = *(const h4*)&base[(ty*27 + tx)*8];
      h2 w2 = __builtin_bit_cast(h2, wgtH[k]);
      accA += w2 * __builtin_shufflevector(g, g, 0, 1);
      accB += w2 * __builtin_shufflevector(g, g, 2, 3);
    }
    int oy = clampi(qi + di - 3, 0, 95), ox = clampi(qj + dj - 3, 0, 95);
    float* ZI = (float*)(ws + O_ZI) + (size_t)b * 16 * HWp + oy*96 + ox;
    int c0 = cq * 4;
    atomicAdd(ZI + (size_t)(c0 + 0) * HWp, (float)accA[0]);
    atomicAdd(ZI + (size_t)(c0 + 1) * HWp, (float)accA[1]);
    atomicAdd(ZI + (size_t)(c0 + 2) * HWp, (float)accB[0]);
    atomicAdd(ZI + (size_t)(c0 + 3) * HWp, (float)accB[1]);
    if (cq == 0) atomicAdd((float*)(ws + O_CT) + (size_t)b * HWp + oy*96 + ox, 1.0f);
  }
}

// ---------- K3: folded epilogue out = B0 + W1·zn + Wv·vid (f32) ----------
__global__ __launch_bounds__(256, 2) void k3_out(const void* vid, float* out, const u8* ws)
{
  __shared__ float znL[16 * 96];
  __shared__ float vidL[64 * 96];
  __shared__ float WvL[32 * 65];
  __shared__ float W1L[32 * 17];
  __shared__ float B0L[32];
  const int tid = threadIdx.x, blk = blockIdx.x;
  const int b = blk / 192, rem = blk % 192, y = rem >> 1, oh = (rem & 1) * 32;
  const float* WT = (const float*)(ws + O_WT);
  const float* ZI = (const float*)(ws + O_ZI) + (size_t)b * 16 * HWp;
  const float* CT = (const float*)(ws + O_CT) + (size_t)b * HWp;
  const bool vf = ((const u32*)(ws + O_FLG))[0] != 0;

  for (int e = tid; e < 1536; e += 256) {
    int c = e / 96, x = e % 96;
    znL[c*96 + x] = ZI[(size_t)c * HWp + y*96 + x] / fmaxf(CT[y*96 + x], 1.f);
  }
  if (vf) {
    const float* v = (const float*)vid;
    for (int e = tid; e < 6144; e += 256) { int c = e / 96, x = e % 96; vidL[c*96 + x] = v[(size_t)(b*64 + c)*HWp + y*96 + x]; }
  } else {
    const u16* v = (const u16*)vid;
    for (int e = tid; e < 6144; e += 256) { int c = e / 96, x = e % 96; vidL[c*96 + x] = bf2f(v[(size_t)(b*64 + c)*HWp + y*96 + x]); }
  }
  for (int e = tid; e < 2048; e += 256) { int o = e >> 6, c = e & 63; WvL[o*65 + c] = WT[W_C + (oh + o)*128 + 64 + c]; }
  for (int e = tid; e < 512; e += 256)  { int o = e >> 4, ci = e & 15; W1L[o*17 + ci] = ((const float*)(ws + O_W1))[(oh + o)*16 + ci]; }
  if (tid < 32) B0L[tid] = ((const float*)(ws + O_B0))[oh + tid];
  __syncthreads();

  const int o = tid >> 3, xq = tid & 7;   // 32 o x 8 xq; 12 x per thread
  f4 a0, a1, a2;
  { float bz = B0L[o]; a0 = bz; a1 = bz; a2 = bz; }
  for (int ci = 0; ci < 16; ++ci) {
    float w = W1L[o*17 + ci];
    const f4* zp = (const f4*)&znL[ci*96 + xq*12];
    a0 += zp[0] * w; a1 += zp[1] * w; a2 += zp[2] * w;
  }
  for (int c = 0; c < 64; ++c) {
    float w = WvL[o*65 + c];
    const f4* vp = (const f4*)&vidL[c*96 + xq*12];
    a0 += vp[0] * w; a1 += vp[1] * w; a2 += vp[2] * w;
  }
  float* op = out + (size_t)(b*64 + oh + o) * HWp + y*96 + xq*12;
  *(f4*)(op + 0) = a0; *(f4*)(op + 4) = a1; *(f4*)(op + 8) = a2;
}

extern "C" void kernel_launch(void* const* d_in, const int* in_sizes, int n_in,
                              void* d_out, int out_size, void* d_ws, size_t ws_size,
                              hipStream_t stream)
{
  (void)in_sizes; (void)n_in; (void)out_size;
  const void* vid  = d_in[0];
  const void* wth  = d_in[1];
  const void* bth  = d_in[2];
  const void* wph  = d_in[3];
  const void* bph  = d_in[4];
  const void* wg   = d_in[5];
  const void* bg   = d_in[6];
  const void* ww   = d_in[7];
  const void* bw   = d_in[8];
  const void* wc33 = d_in[9];
  const void* bc33 = d_in[10];
  u8* ws = (u8*)d_ws;
  if (ws_size < WS_NEED) return;

  hipLaunchKernelGGL(kz_prep, dim3(1225), dim3(256), 0, stream,
                     vid, wth, bth, wph, bph, wg, bg, ww, bw, wc33, bc33, ws);
  hipLaunchKernelGGL(k1_conv, dim3(288), dim3(256), 0, stream, vid, ws);
  hipLaunchKernelGGL(k2_attn, dim3(1152), dim3(256), 0, stream, ws);
  hipLaunchKernelGGL(k3_out, dim3(384), dim3(256), 0, stream, vid, (float*)d_out, ws);
}